// Round 1
// baseline (424.152 us; speedup 1.0000x reference)
//
#include <hip/hip_runtime.h>
#include <hip/hip_bf16.h>
#include <math.h>

#define NROWS 4096
#define DDIM  512
static constexpr float ALPHA = 10.0f;
static constexpr float BETA  = 2.0f;
static constexpr float BASE  = 0.5f;

// ---- sortable-uint encoding for float atomic min/max ----
__device__ __forceinline__ unsigned enc_f32(float f) {
  unsigned b = __float_as_uint(f);
  return (b & 0x80000000u) ? ~b : (b | 0x80000000u);
}
__device__ __forceinline__ float dec_f32(unsigned u) {
  unsigned b = (u & 0x80000000u) ? (u & 0x7fffffffu) : ~u;
  return __uint_as_float(b);
}

// enc(+inf) = 0xFF800000 ; enc(-inf) = 0x007FFFFF
__global__ __launch_bounds__(256) void init_ws_k(unsigned* __restrict__ minb,
                                                 unsigned* __restrict__ maxb,
                                                 float* __restrict__ ps,
                                                 float* __restrict__ ns,
                                                 float* __restrict__ lacc) {
  int i = blockIdx.x * 256 + threadIdx.x;
  if (i < NROWS) {
    minb[i] = 0xFF800000u;  // enc(+inf)
    maxb[i] = 0x007FFFFFu;  // enc(-inf)
    ps[i] = 0.0f;
    ns[i] = 0.0f;
  }
  if (i < 8) lacc[i] = 0.0f;
}

__device__ __forceinline__ float block_sum(float v) {
  __shared__ float sh[4];
  #pragma unroll
  for (int off = 32; off > 0; off >>= 1) v += __shfl_down(v, off);
  if ((threadIdx.x & 63) == 0) sh[threadIdx.x >> 6] = v;
  __syncthreads();
  float r = sh[0] + sh[1] + sh[2] + sh[3];
  __syncthreads();  // allow reuse of sh on subsequent calls
  return r;
}

// MODE 0: min/max epilogue only (pass A, no sim store)
// MODE 1: min/max epilogue + store sim to ws     (pass A, materialized)
// MODE 2: exp-sum epilogue (pass B recompute path)
template <int MODE>
__global__ __launch_bounds__(256) void gemm_fused(
    const float* __restrict__ X, const int* __restrict__ tgt,
    const float* __restrict__ marginp,
    unsigned* __restrict__ minb, unsigned* __restrict__ maxb,
    float* __restrict__ ps, float* __restrict__ ns,
    float* __restrict__ lacc, float* __restrict__ sim) {
  __shared__ float As[64][33];
  __shared__ float Bs[64][33];
  const int tid = threadIdx.x;
  const int tx = tid & 15, ty = tid >> 4;
  const int i0 = (blockIdx.x >> 6) << 6;
  const int j0 = (blockIdx.x & 63) << 6;
  const int ty4 = ty << 2, tx4 = tx << 2;

  float acc[4][4] = {};

  for (int k0 = 0; k0 < DDIM; k0 += 32) {
    #pragma unroll
    for (int l = 0; l < 2; ++l) {
      const int q = tid + (l << 8);
      const int r = q >> 3;
      const int c = (q & 7) << 2;
      const float4 va = *reinterpret_cast<const float4*>(X + (size_t)(i0 + r) * DDIM + k0 + c);
      As[r][c + 0] = va.x; As[r][c + 1] = va.y; As[r][c + 2] = va.z; As[r][c + 3] = va.w;
      const float4 vb = *reinterpret_cast<const float4*>(X + (size_t)(j0 + r) * DDIM + k0 + c);
      Bs[r][c + 0] = vb.x; Bs[r][c + 1] = vb.y; Bs[r][c + 2] = vb.z; Bs[r][c + 3] = vb.w;
    }
    __syncthreads();
    #pragma unroll
    for (int k = 0; k < 32; ++k) {
      const float a0 = As[ty4 + 0][k], a1 = As[ty4 + 1][k];
      const float a2 = As[ty4 + 2][k], a3 = As[ty4 + 3][k];
      const float b0 = Bs[tx4 + 0][k], b1 = Bs[tx4 + 1][k];
      const float b2 = Bs[tx4 + 2][k], b3 = Bs[tx4 + 3][k];
      acc[0][0] = fmaf(a0, b0, acc[0][0]); acc[0][1] = fmaf(a0, b1, acc[0][1]);
      acc[0][2] = fmaf(a0, b2, acc[0][2]); acc[0][3] = fmaf(a0, b3, acc[0][3]);
      acc[1][0] = fmaf(a1, b0, acc[1][0]); acc[1][1] = fmaf(a1, b1, acc[1][1]);
      acc[1][2] = fmaf(a1, b2, acc[1][2]); acc[1][3] = fmaf(a1, b3, acc[1][3]);
      acc[2][0] = fmaf(a2, b0, acc[2][0]); acc[2][1] = fmaf(a2, b1, acc[2][1]);
      acc[2][2] = fmaf(a2, b2, acc[2][2]); acc[2][3] = fmaf(a2, b3, acc[2][3]);
      acc[3][0] = fmaf(a3, b0, acc[3][0]); acc[3][1] = fmaf(a3, b1, acc[3][1]);
      acc[3][2] = fmaf(a3, b2, acc[3][2]); acc[3][3] = fmaf(a3, b3, acc[3][3]);
    }
    __syncthreads();
  }

  int ti[4], tj[4];
  #pragma unroll
  for (int m = 0; m < 4; ++m) ti[m] = tgt[i0 + ty4 + m];
  #pragma unroll
  for (int n = 0; n < 4; ++n) tj[n] = tgt[j0 + tx4 + n];

  if constexpr (MODE == 1) {
    #pragma unroll
    for (int m = 0; m < 4; ++m) {
      float4 v = make_float4(acc[m][0], acc[m][1], acc[m][2], acc[m][3]);
      *reinterpret_cast<float4*>(sim + (size_t)(i0 + ty4 + m) * NROWS + j0 + tx4) = v;
    }
  }

  if constexpr (MODE == 0 || MODE == 1) {
    #pragma unroll
    for (int m = 0; m < 4; ++m) {
      float mnp = INFINITY, mxn = -INFINITY;
      #pragma unroll
      for (int n = 0; n < 4; ++n) {
        const float s = acc[m][n];
        if (ti[m] == tj[n]) {
          if (s < 1.0f) mnp = fminf(mnp, s);
        } else {
          mxn = fmaxf(mxn, s);
        }
      }
      #pragma unroll
      for (int off = 1; off < 16; off <<= 1) {
        mnp = fminf(mnp, __shfl_xor(mnp, off));
        mxn = fmaxf(mxn, __shfl_xor(mxn, off));
      }
      if (tx == 0) {
        atomicMin(minb + i0 + ty4 + m, enc_f32(mnp));
        atomicMax(maxb + i0 + ty4 + m, enc_f32(mxn));
      }
    }
  }

  if constexpr (MODE == 2) {
    const float margin = *marginp;
    #pragma unroll
    for (int m = 0; m < 4; ++m) {
      const int row = i0 + ty4 + m;
      const float mp = dec_f32(minb[row]);
      const float mx = dec_f32(maxb[row]);
      float psum = 0.0f, nsum = 0.0f;
      #pragma unroll
      for (int n = 0; n < 4; ++n) {
        const float s = acc[m][n];
        if (ti[m] != tj[n]) {
          if (s + margin - mp > 0.0f) nsum += expf(ALPHA * (s - BASE));
        } else if (s < 1.0f) {
          if (mx - s + margin > 0.0f) psum += expf(-BETA * (s - BASE));
        }
      }
      #pragma unroll
      for (int off = 1; off < 16; off <<= 1) {
        psum += __shfl_xor(psum, off);
        nsum += __shfl_xor(nsum, off);
      }
      if (tx == 0) {
        atomicAdd(ps + row, psum);
        atomicAdd(ns + row, nsum);
      }
      if (row == NROWS - 1) {  // last-row pre-mining stats (uniform over the 16-lane group)
        float lsp = 0.0f, lcp = 0.0f, lsn = 0.0f, lcn = 0.0f;
        #pragma unroll
        for (int n = 0; n < 4; ++n) {
          const float s = acc[m][n];
          if (ti[m] != tj[n]) { lsn += s; lcn += 1.0f; }
          else if (s < 1.0f)  { lsp += s; lcp += 1.0f; }
        }
        #pragma unroll
        for (int off = 1; off < 16; off <<= 1) {
          lsp += __shfl_xor(lsp, off); lcp += __shfl_xor(lcp, off);
          lsn += __shfl_xor(lsn, off); lcn += __shfl_xor(lcn, off);
        }
        if (tx == 0) {
          atomicAdd(lacc + 0, lsp); atomicAdd(lacc + 1, lcp);
          atomicAdd(lacc + 2, lsn); atomicAdd(lacc + 3, lcn);
        }
      }
    }
  }
}

// Pass B when sim is materialized: one block per row.
__global__ __launch_bounds__(256) void row_pass(
    const float* __restrict__ sim, const int* __restrict__ tgt,
    const unsigned* __restrict__ minb, const unsigned* __restrict__ maxb,
    float* __restrict__ ps, float* __restrict__ ns,
    float* __restrict__ lacc, const float* __restrict__ marginp) {
  const int i = blockIdx.x;
  const int ti = tgt[i];
  const float mp = dec_f32(minb[i]);
  const float mx = dec_f32(maxb[i]);
  const float margin = *marginp;
  const float* row = sim + (size_t)i * NROWS;
  float psum = 0.0f, nsum = 0.0f, lsp = 0.0f, lcp = 0.0f, lsn = 0.0f, lcn = 0.0f;
  for (int j = threadIdx.x; j < NROWS; j += 256) {
    const float s = row[j];
    if (tgt[j] != ti) {
      if (s + margin - mp > 0.0f) nsum += expf(ALPHA * (s - BASE));
      if (i == NROWS - 1) { lsn += s; lcn += 1.0f; }
    } else if (s < 1.0f) {
      if (mx - s + margin > 0.0f) psum += expf(-BETA * (s - BASE));
      if (i == NROWS - 1) { lsp += s; lcp += 1.0f; }
    }
  }
  psum = block_sum(psum);
  nsum = block_sum(nsum);
  if (i == NROWS - 1) {
    lsp = block_sum(lsp); lcp = block_sum(lcp);
    lsn = block_sum(lsn); lcn = block_sum(lcn);
  }
  if (threadIdx.x == 0) {
    ps[i] = psum;
    ns[i] = nsum;
    if (i == NROWS - 1) { lacc[0] = lsp; lacc[1] = lcp; lacc[2] = lsn; lacc[3] = lcn; }
  }
}

__global__ __launch_bounds__(256) void finalize_k(
    const float* __restrict__ ps, const float* __restrict__ ns,
    const float* __restrict__ lacc, float* __restrict__ out) {
  float lsum = 0.0f, inval = 0.0f;
  for (int i = threadIdx.x; i < NROWS; i += 256) {
    const float p = ps[i], q = ns[i];
    if (p > 0.0f && q > 0.0f) {
      lsum += (2.0f / BETA) * log1pf(p) + (2.0f / ALPHA) * log1pf(q);
    } else {
      inval += 1.0f;
    }
  }
  lsum = block_sum(lsum);
  inval = block_sum(inval);
  if (threadIdx.x == 0) {
    out[0] = lsum / (float)NROWS;
    out[1] = inval / (float)NROWS;
    out[2] = lacc[0] / fmaxf(lacc[1], 1.0f);
    out[3] = lacc[2] / fmaxf(lacc[3], 1.0f);
  }
}

extern "C" void kernel_launch(void* const* d_in, const int* in_sizes, int n_in,
                              void* d_out, int out_size, void* d_ws, size_t ws_size,
                              hipStream_t stream) {
  const float* X = (const float*)d_in[0];
  const int* tgt = (const int*)d_in[1];
  const float* marginp = (const float*)d_in[2];
  float* out = (float*)d_out;

  unsigned* minb = (unsigned*)d_ws;
  unsigned* maxb = minb + NROWS;
  float* ps = (float*)(maxb + NROWS);
  float* ns = ps + NROWS;
  float* lacc = ns + NROWS;
  float* sim = (float*)((char*)d_ws + (size_t)(128 << 10));
  const bool fits = ws_size >= (size_t)(128 << 10) + (size_t)NROWS * NROWS * 4;

  init_ws_k<<<dim3((NROWS + 255) / 256), 256, 0, stream>>>(minb, maxb, ps, ns, lacc);

  if (fits) {
    gemm_fused<1><<<dim3(64 * 64), 256, 0, stream>>>(X, tgt, marginp, minb, maxb, ps, ns, lacc, sim);
    row_pass<<<dim3(NROWS), 256, 0, stream>>>(sim, tgt, minb, maxb, ps, ns, lacc, marginp);
  } else {
    gemm_fused<0><<<dim3(64 * 64), 256, 0, stream>>>(X, tgt, marginp, minb, maxb, ps, ns, lacc, nullptr);
    gemm_fused<2><<<dim3(64 * 64), 256, 0, stream>>>(X, tgt, marginp, minb, maxb, ps, ns, lacc, nullptr);
  }
  finalize_k<<<dim3(1), 256, 0, stream>>>(ps, ns, lacc, out);
}

// Round 2
// 142.545 us; speedup vs baseline: 2.9756x; 2.9756x over previous
//
#include <hip/hip_runtime.h>
#include <hip/hip_bf16.h>
#include <math.h>

#define NROWS 4096
#define DDIM  512
static constexpr float ALPHA = 10.0f;
static constexpr float BETA  = 2.0f;
static constexpr float BASE  = 0.5f;

typedef short bf16x8 __attribute__((ext_vector_type(8)));
typedef float f32x4 __attribute__((ext_vector_type(4)));

// ---- sortable-uint encoding for float atomic min/max ----
__device__ __forceinline__ unsigned enc_f32(float f) {
  unsigned b = __float_as_uint(f);
  return (b & 0x80000000u) ? ~b : (b | 0x80000000u);
}
__device__ __forceinline__ float dec_f32(unsigned u) {
  unsigned b = (u & 0x80000000u) ? (u & 0x7fffffffu) : ~u;
  return __uint_as_float(b);
}
__device__ __forceinline__ unsigned short f2bf(float f) {
  __hip_bfloat16 h = __float2bfloat16(f);  // RNE
  return *reinterpret_cast<unsigned short*>(&h);
}
__device__ __forceinline__ float bf2f(unsigned short u) {
  return __uint_as_float(((unsigned)u) << 16);
}

#define GLOAD_LDS16(g, l)                                              \
  __builtin_amdgcn_global_load_lds(                                    \
      (const __attribute__((address_space(1))) void*)(g),              \
      (__attribute__((address_space(3))) void*)(l), 16, 0, 0)

__global__ __launch_bounds__(256) void init_k(unsigned* __restrict__ minb,
                                              unsigned* __restrict__ maxb) {
  int i = blockIdx.x * 256 + threadIdx.x;
  if (i < NROWS) {
    minb[i] = 0xFF800000u;  // enc(+inf)
    maxb[i] = 0x007FFFFFu;  // enc(-inf)
  }
}

__device__ __forceinline__ float block_sum(float v) {
  __shared__ float sh[4];
  #pragma unroll
  for (int off = 32; off > 0; off >>= 1) v += __shfl_down(v, off);
  if ((threadIdx.x & 63) == 0) sh[threadIdx.x >> 6] = v;
  __syncthreads();
  float r = sh[0] + sh[1] + sh[2] + sh[3];
  __syncthreads();
  return r;
}

// X f32 -> Xb bf16; also f32 self-dot per row (for diagonal override).
__global__ __launch_bounds__(256) void convert_k(const float* __restrict__ X,
                                                 unsigned short* __restrict__ Xb,
                                                 float* __restrict__ selfsim) {
  const int r = blockIdx.x;
  const int t = threadIdx.x;
  float sd = 0.0f;
  #pragma unroll
  for (int h = 0; h < 2; ++h) {
    const int e = t + h * 256;
    const float v = X[(size_t)r * DDIM + e];
    Xb[(size_t)r * DDIM + e] = f2bf(v);
    sd = fmaf(v, v, sd);
  }
  sd = block_sum(sd);
  if (t == 0) selfsim[r] = sd;
}

// 128x128-tile bf16 MFMA GEMM (C = Xb * Xb^T), fused epilogue:
//   - diagonal override with f32 self-dot
//   - store sim as bf16 to ws
//   - per-row masked min(pos)/max(neg) via 16-lane shfl reduce + atomics
__global__ __launch_bounds__(256) void gemm_mfma(
    const unsigned short* __restrict__ Xb, const int* __restrict__ tgt,
    const float* __restrict__ selfsim,
    unsigned* __restrict__ minb, unsigned* __restrict__ maxb,
    unsigned short* __restrict__ simb) {
  __shared__ unsigned short As[128 * 32] __attribute__((aligned(16)));
  __shared__ unsigned short Bs[128 * 32] __attribute__((aligned(16)));

  const int tid = threadIdx.x;
  const int w = tid >> 6;          // wave 0..3
  const int lane = tid & 63;
  const int wr = w >> 1, wc = w & 1;
  const int g = lane >> 4, q = lane & 15;

  const int i0 = (blockIdx.x >> 5) << 7;   // 32x32 block grid, 128 rows per tile
  const int j0 = (blockIdx.x & 31) << 7;

  const char* Xbb = (const char*)Xb;

  f32x4 acc[4][4];
  #pragma unroll
  for (int m = 0; m < 4; ++m)
    #pragma unroll
    for (int n = 0; n < 4; ++n)
      acc[m][n] = (f32x4)0.0f;

  for (int k0 = 0; k0 < DDIM; k0 += 32) {
    // ---- stage A and B tiles via global_load_lds (width 16) ----
    #pragma unroll
    for (int c = 0; c < 2; ++c) {
      const int lin = c * 4096 + w * 1024 + lane * 16;  // byte offset in tile
      const int row = lin >> 6;                         // 64 B per row (32 bf16)
      const int col = lin & 63;
      GLOAD_LDS16(Xbb + (size_t)(i0 + row) * (DDIM * 2) + k0 * 2 + col,
                  (char*)As + lin);
      GLOAD_LDS16(Xbb + (size_t)(j0 + row) * (DDIM * 2) + k0 * 2 + col,
                  (char*)Bs + lin);
    }
    __syncthreads();

    bf16x8 a[4], b[4];
    #pragma unroll
    for (int fm = 0; fm < 4; ++fm)
      a[fm] = *reinterpret_cast<const bf16x8*>(As + (wr * 64 + fm * 16 + q) * 32 + g * 8);
    #pragma unroll
    for (int fn = 0; fn < 4; ++fn)
      b[fn] = *reinterpret_cast<const bf16x8*>(Bs + (wc * 64 + fn * 16 + q) * 32 + g * 8);
    #pragma unroll
    for (int fm = 0; fm < 4; ++fm)
      #pragma unroll
      for (int fn = 0; fn < 4; ++fn)
        acc[fm][fn] = __builtin_amdgcn_mfma_f32_16x16x32_bf16(a[fm], b[fn], acc[fm][fn], 0, 0, 0);
    __syncthreads();
  }

  // ---- fused epilogue ----
  int cg[4], tj[4];
  #pragma unroll
  for (int fn = 0; fn < 4; ++fn) {
    cg[fn] = j0 + wc * 64 + fn * 16 + q;
    tj[fn] = tgt[cg[fn]];
  }

  #pragma unroll
  for (int fm = 0; fm < 4; ++fm) {
    #pragma unroll
    for (int reg = 0; reg < 4; ++reg) {
      const int r = i0 + wr * 64 + fm * 16 + g * 4 + reg;
      const int tr = tgt[r];
      float mnp = INFINITY, mxn = -INFINITY;
      #pragma unroll
      for (int fn = 0; fn < 4; ++fn) {
        float s = acc[fm][fn][reg];
        if (r == cg[fn]) s = selfsim[r];  // f32 diagonal override
        simb[(size_t)r * NROWS + cg[fn]] = f2bf(s);
        if (tj[fn] == tr) {
          if (s < 1.0f) mnp = fminf(mnp, s);
        } else {
          mxn = fmaxf(mxn, s);
        }
      }
      #pragma unroll
      for (int off = 1; off < 16; off <<= 1) {
        mnp = fminf(mnp, __shfl_xor(mnp, off));
        mxn = fmaxf(mxn, __shfl_xor(mxn, off));
      }
      if (q == 0) {
        atomicMin(minb + r, enc_f32(mnp));
        atomicMax(maxb + r, enc_f32(mxn));
      }
    }
  }
}

// One block per row over materialized bf16 sim.
__global__ __launch_bounds__(256) void row_pass(
    const unsigned short* __restrict__ simb, const int* __restrict__ tgt,
    const unsigned* __restrict__ minb, const unsigned* __restrict__ maxb,
    float* __restrict__ ps, float* __restrict__ ns,
    float* __restrict__ lacc, const float* __restrict__ marginp) {
  const int i = blockIdx.x;
  const int ti = tgt[i];
  const float mp = dec_f32(minb[i]);
  const float mx = dec_f32(maxb[i]);
  const float margin = *marginp;
  const unsigned short* row = simb + (size_t)i * NROWS;
  const int j0 = threadIdx.x * 16;  // 256 threads x 16 = 4096

  float psum = 0.0f, nsum = 0.0f, lsp = 0.0f, lcp = 0.0f, lsn = 0.0f, lcn = 0.0f;
  bf16x8 v[2];
  v[0] = *reinterpret_cast<const bf16x8*>(row + j0);
  v[1] = *reinterpret_cast<const bf16x8*>(row + j0 + 8);
  int tj[16];
  #pragma unroll
  for (int m = 0; m < 4; ++m) {
    const int4 t4 = *reinterpret_cast<const int4*>(tgt + j0 + 4 * m);
    tj[4 * m + 0] = t4.x; tj[4 * m + 1] = t4.y; tj[4 * m + 2] = t4.z; tj[4 * m + 3] = t4.w;
  }
  #pragma unroll
  for (int e = 0; e < 16; ++e) {
    const float s = bf2f((unsigned short)v[e >> 3][e & 7]);
    if (tj[e] != ti) {
      if (s + margin - mp > 0.0f) nsum += __expf(ALPHA * (s - BASE));
      if (i == NROWS - 1) { lsn += s; lcn += 1.0f; }
    } else if (s < 1.0f) {
      if (mx - s + margin > 0.0f) psum += __expf(-BETA * (s - BASE));
      if (i == NROWS - 1) { lsp += s; lcp += 1.0f; }
    }
  }
  psum = block_sum(psum);
  nsum = block_sum(nsum);
  if (i == NROWS - 1) {
    lsp = block_sum(lsp); lcp = block_sum(lcp);
    lsn = block_sum(lsn); lcn = block_sum(lcn);
  }
  if (threadIdx.x == 0) {
    ps[i] = psum;
    ns[i] = nsum;
    if (i == NROWS - 1) { lacc[0] = lsp; lacc[1] = lcp; lacc[2] = lsn; lacc[3] = lcn; }
  }
}

__global__ __launch_bounds__(256) void finalize_k(
    const float* __restrict__ ps, const float* __restrict__ ns,
    const float* __restrict__ lacc, float* __restrict__ out) {
  float lsum = 0.0f, inval = 0.0f;
  for (int i = threadIdx.x; i < NROWS; i += 256) {
    const float p = ps[i], q = ns[i];
    if (p > 0.0f && q > 0.0f) {
      lsum += (2.0f / BETA) * log1pf(p) + (2.0f / ALPHA) * log1pf(q);
    } else {
      inval += 1.0f;
    }
  }
  lsum = block_sum(lsum);
  inval = block_sum(inval);
  if (threadIdx.x == 0) {
    out[0] = lsum / (float)NROWS;
    out[1] = inval / (float)NROWS;
    out[2] = lacc[0] / fmaxf(lacc[1], 1.0f);
    out[3] = lacc[2] / fmaxf(lacc[3], 1.0f);
  }
}

extern "C" void kernel_launch(void* const* d_in, const int* in_sizes, int n_in,
                              void* d_out, int out_size, void* d_ws, size_t ws_size,
                              hipStream_t stream) {
  const float* X = (const float*)d_in[0];
  const int* tgt = (const int*)d_in[1];
  const float* marginp = (const float*)d_in[2];
  float* out = (float*)d_out;

  char* ws = (char*)d_ws;
  unsigned* minb = (unsigned*)ws;                        // 16 KB
  unsigned* maxb = (unsigned*)(ws + (16 << 10));         // 16 KB
  float* ps = (float*)(ws + (32 << 10));                 // 16 KB
  float* ns = (float*)(ws + (48 << 10));                 // 16 KB
  float* lacc = (float*)(ws + (64 << 10));               // small
  float* selfsim = (float*)(ws + (80 << 10));            // 16 KB
  unsigned short* Xb = (unsigned short*)(ws + (128 << 10));          // 4 MB
  unsigned short* simb = (unsigned short*)(ws + (128 << 10) + ((size_t)4 << 20));  // 32 MB

  init_k<<<dim3(16), 256, 0, stream>>>(minb, maxb);
  convert_k<<<dim3(NROWS), 256, 0, stream>>>(X, Xb, selfsim);
  gemm_mfma<<<dim3(32 * 32), 256, 0, stream>>>(Xb, tgt, selfsim, minb, maxb, simb);
  row_pass<<<dim3(NROWS), 256, 0, stream>>>(simb, tgt, minb, maxb, ps, ns, lacc, marginp);
  finalize_k<<<dim3(1), 256, 0, stream>>>(ps, ns, lacc, out);
}

// Round 3
// 124.781 us; speedup vs baseline: 3.3992x; 1.1424x over previous
//
#include <hip/hip_runtime.h>
#include <hip/hip_bf16.h>
#include <math.h>

#define NROWS 4096
#define DDIM  512
#define BM    128
#define BK    64
#define NT    (DDIM / BK)            // 8 K-steps
#define NBLK  (NROWS / BM)           // 32
#define NTRI  (NBLK * (NBLK + 1) / 2)  // 528 upper-triangle blocks

static constexpr float ALPHA = 10.0f;
static constexpr float BETA  = 2.0f;
static constexpr float BASE  = 0.5f;

typedef short bf16x8 __attribute__((ext_vector_type(8)));
typedef float f32x4 __attribute__((ext_vector_type(4)));

// ---- sortable-uint encoding for float atomic min/max ----
__device__ __forceinline__ unsigned enc_f32(float f) {
  unsigned b = __float_as_uint(f);
  return (b & 0x80000000u) ? ~b : (b | 0x80000000u);
}
__device__ __forceinline__ float dec_f32(unsigned u) {
  unsigned b = (u & 0x80000000u) ? (u & 0x7fffffffu) : ~u;
  return __uint_as_float(b);
}
__device__ __forceinline__ unsigned f2bf(float f) {
  __hip_bfloat16 h = __float2bfloat16(f);  // RNE
  return (unsigned)*reinterpret_cast<unsigned short*>(&h);
}
__device__ __forceinline__ float bf2f(unsigned short u) {
  return __uint_as_float(((unsigned)u) << 16);
}

#define GLOAD_LDS16(g, l)                                              \
  __builtin_amdgcn_global_load_lds(                                    \
      (const __attribute__((address_space(1))) void*)(g),              \
      (__attribute__((address_space(3))) void*)(l), 16, 0, 0)

// ---- convert X f32 -> bf16 (packed), f32 self-dot per row, init min/max ----
// grid 1024 x 256; wave-per-row (4 rows/block)
__global__ __launch_bounds__(256) void convert_k(
    const float* __restrict__ X, unsigned short* __restrict__ Xb,
    float* __restrict__ selfsim, unsigned* __restrict__ minb,
    unsigned* __restrict__ maxb, float* __restrict__ lacc) {
  const int gid = blockIdx.x * 256 + threadIdx.x;
  if (gid < NROWS) {
    minb[gid] = 0xFF800000u;  // enc(+inf)
    maxb[gid] = 0x007FFFFFu;  // enc(-inf)
  }
  if (gid < 8) lacc[gid] = 0.0f;

  const int wid = threadIdx.x >> 6, lane = threadIdx.x & 63;
  const int r = blockIdx.x * 4 + wid;
  const size_t base = (size_t)r * DDIM + lane * 8;
  const float4 v0 = *reinterpret_cast<const float4*>(X + base);
  const float4 v1 = *reinterpret_cast<const float4*>(X + base + 4);
  uint4 u;
  u.x = f2bf(v0.x) | (f2bf(v0.y) << 16);
  u.y = f2bf(v0.z) | (f2bf(v0.w) << 16);
  u.z = f2bf(v1.x) | (f2bf(v1.y) << 16);
  u.w = f2bf(v1.z) | (f2bf(v1.w) << 16);
  *reinterpret_cast<uint4*>(Xb + base) = u;

  float sd = v0.x * v0.x;
  sd = fmaf(v0.y, v0.y, sd); sd = fmaf(v0.z, v0.z, sd); sd = fmaf(v0.w, v0.w, sd);
  sd = fmaf(v1.x, v1.x, sd); sd = fmaf(v1.y, v1.y, sd);
  sd = fmaf(v1.z, v1.z, sd); sd = fmaf(v1.w, v1.w, sd);
  #pragma unroll
  for (int off = 1; off < 64; off <<= 1) sd += __shfl_xor(sd, off);
  if (lane == 0) selfsim[r] = sd;
}

// ---- upper-triangle 128x128 MFMA GEMM, dbuf BK=64, swizzled LDS ----
__global__ __launch_bounds__(256) void gemm_tri(
    const unsigned short* __restrict__ Xb, const int* __restrict__ tgt,
    const float* __restrict__ selfsim,
    unsigned* __restrict__ minb, unsigned* __restrict__ maxb,
    unsigned short* __restrict__ simb) {
  __shared__ unsigned short lds[2][2][BM * BK] __attribute__((aligned(16)));  // 64 KB

  // blockIdx -> (bi, bj), bi <= bj
  int kk0 = blockIdx.x, bi = 0;
  while (kk0 >= NBLK - bi) { kk0 -= NBLK - bi; ++bi; }
  const int bj = bi + kk0;
  const int i0 = bi * BM, j0 = bj * BM;
  const bool diagb = (bi == bj);

  const int tid = threadIdx.x;
  const int w = tid >> 6, lane = tid & 63;
  const int wr = w >> 1, wc = w & 1;
  const int g = lane >> 4, q = lane & 15;
  const char* Xbb = (const char*)Xb;

  f32x4 acc[4][4];
  #pragma unroll
  for (int m = 0; m < 4; ++m)
    #pragma unroll
    for (int n = 0; n < 4; ++n) acc[m][n] = (f32x4)0.0f;

  // stage tile t into buffer buf (pre-swizzled global source, linear LDS dest)
  #define STAGE(buf, t)                                                          \
    do {                                                                         \
      const int kb_ = (t) * (BK * 2);                                            \
      _Pragma("unroll")                                                          \
      for (int c_ = 0; c_ < 4; ++c_) {                                           \
        const int lin_ = (c_ * 256 + tid) * 16;                                  \
        const int row_ = lin_ >> 7;                                              \
        const int col_ = lin_ & 127;                                             \
        const int scol_ = col_ ^ ((row_ & 7) << 4);                              \
        GLOAD_LDS16(Xbb + (size_t)(i0 + row_) * (DDIM * 2) + kb_ + scol_,        \
                    (char*)&lds[buf][0][0] + lin_);                              \
        GLOAD_LDS16(Xbb + (size_t)(j0 + row_) * (DDIM * 2) + kb_ + scol_,        \
                    (char*)&lds[buf][1][0] + lin_);                              \
      }                                                                          \
    } while (0)

  STAGE(0, 0);
  __syncthreads();
  int cur = 0;
  for (int t = 0; t < NT; ++t) {
    if (t + 1 < NT) STAGE(cur ^ 1, t + 1);  // issue next-tile loads (overlap)
    const char* Ab = (const char*)&lds[cur][0][0];
    const char* Bb = (const char*)&lds[cur][1][0];
    #pragma unroll
    for (int kk = 0; kk < 2; ++kk) {
      bf16x8 a[4], b[4];
      #pragma unroll
      for (int fm = 0; fm < 4; ++fm) {
        const int row = wr * 64 + fm * 16 + q;
        const int col = (kk * 64 + g * 16) ^ ((row & 7) << 4);
        a[fm] = *reinterpret_cast<const bf16x8*>(Ab + row * 128 + col);
      }
      #pragma unroll
      for (int fn = 0; fn < 4; ++fn) {
        const int row = wc * 64 + fn * 16 + q;
        const int col = (kk * 64 + g * 16) ^ ((row & 7) << 4);
        b[fn] = *reinterpret_cast<const bf16x8*>(Bb + row * 128 + col);
      }
      #pragma unroll
      for (int fm = 0; fm < 4; ++fm)
        #pragma unroll
        for (int fn = 0; fn < 4; ++fn)
          acc[fm][fn] = __builtin_amdgcn_mfma_f32_16x16x32_bf16(a[fm], b[fn], acc[fm][fn], 0, 0, 0);
    }
    __syncthreads();  // drains vmcnt(0): next buffer staged, current reads done
    cur ^= 1;
  }

  // ---- epilogue ----
  const int rbase = i0 + wr * 64;
  int cg[4], tj[4];
  #pragma unroll
  for (int fn = 0; fn < 4; ++fn) {
    cg[fn] = j0 + wc * 64 + fn * 16 + q;
    tj[fn] = tgt[cg[fn]];
  }
  int ti[16];
  #pragma unroll
  for (int fm = 0; fm < 4; ++fm)
    #pragma unroll
    for (int reg = 0; reg < 4; ++reg)
      ti[fm * 4 + reg] = tgt[rbase + fm * 16 + g * 4 + reg];

  // row-side min/max + normal-orientation store
  #pragma unroll
  for (int fm = 0; fm < 4; ++fm) {
    #pragma unroll
    for (int reg = 0; reg < 4; ++reg) {
      const int r = rbase + fm * 16 + g * 4 + reg;
      const int tr = ti[fm * 4 + reg];
      float mnp = INFINITY, mxn = -INFINITY;
      #pragma unroll
      for (int fn = 0; fn < 4; ++fn) {
        float s = acc[fm][fn][reg];
        if (diagb && r == cg[fn]) s = selfsim[r];  // f32 diagonal override
        simb[(size_t)r * NROWS + cg[fn]] = (unsigned short)f2bf(s);
        if (tj[fn] == tr) {
          if (s < 1.0f) mnp = fminf(mnp, s);
        } else {
          mxn = fmaxf(mxn, s);
        }
      }
      #pragma unroll
      for (int off = 1; off < 16; off <<= 1) {
        mnp = fminf(mnp, __shfl_xor(mnp, off));
        mxn = fmaxf(mxn, __shfl_xor(mxn, off));
      }
      if (q == 0) {
        atomicMin(minb + r, enc_f32(mnp));
        atomicMax(maxb + r, enc_f32(mxn));
      }
    }
  }

  if (!diagb) {
    // col-side min/max (reduce across g: lanes stride 16)
    #pragma unroll
    for (int fn = 0; fn < 4; ++fn) {
      const int c = cg[fn];
      const int tc = tj[fn];
      float mnp = INFINITY, mxn = -INFINITY;
      #pragma unroll
      for (int fm = 0; fm < 4; ++fm)
        #pragma unroll
        for (int reg = 0; reg < 4; ++reg) {
          const float s = acc[fm][fn][reg];
          if (ti[fm * 4 + reg] == tc) {
            if (s < 1.0f) mnp = fminf(mnp, s);
          } else {
            mxn = fmaxf(mxn, s);
          }
        }
      mnp = fminf(mnp, __shfl_xor(mnp, 16));
      mnp = fminf(mnp, __shfl_xor(mnp, 32));
      mxn = fmaxf(mxn, __shfl_xor(mxn, 16));
      mxn = fmaxf(mxn, __shfl_xor(mxn, 32));
      if (lane < 16) {
        atomicMin(minb + c, enc_f32(mnp));
        atomicMax(maxb + c, enc_f32(mxn));
      }
    }
    // transposed-orientation store: acc regs 0..3 are col-adjacent -> packed 8B
    #pragma unroll
    for (int fm = 0; fm < 4; ++fm)
      #pragma unroll
      for (int fn = 0; fn < 4; ++fn) {
        uint2 uu;
        uu.x = f2bf(acc[fm][fn][0]) | (f2bf(acc[fm][fn][1]) << 16);
        uu.y = f2bf(acc[fm][fn][2]) | (f2bf(acc[fm][fn][3]) << 16);
        *reinterpret_cast<uint2*>(simb + (size_t)cg[fn] * NROWS + rbase + fm * 16 + g * 4) = uu;
      }
  }
}

// ---- per-row pass over materialized bf16 sim: wave-per-row ----
__global__ __launch_bounds__(256) void row_pass(
    const unsigned short* __restrict__ simb, const int* __restrict__ tgt,
    const unsigned* __restrict__ minb, const unsigned* __restrict__ maxb,
    float* __restrict__ rowloss, float* __restrict__ rowvalid,
    float* __restrict__ lacc, const float* __restrict__ marginp) {
  const int wid = threadIdx.x >> 6, lane = threadIdx.x & 63;
  const int i = blockIdx.x * 4 + wid;
  const int ti = tgt[i];
  const float mp = dec_f32(minb[i]);
  const float mx = dec_f32(maxb[i]);
  const float margin = *marginp;
  const unsigned short* row = simb + (size_t)i * NROWS;
  const bool last = (i == NROWS - 1);

  float psum = 0.0f, nsum = 0.0f, lsp = 0.0f, lcp = 0.0f, lsn = 0.0f, lcn = 0.0f;
  #pragma unroll
  for (int c = 0; c < 8; ++c) {
    const int j0 = c * 512 + lane * 8;
    const bf16x8 v = *reinterpret_cast<const bf16x8*>(row + j0);
    const int4 t0 = *reinterpret_cast<const int4*>(tgt + j0);
    const int4 t1 = *reinterpret_cast<const int4*>(tgt + j0 + 4);
    const int tj[8] = {t0.x, t0.y, t0.z, t0.w, t1.x, t1.y, t1.z, t1.w};
    #pragma unroll
    for (int e = 0; e < 8; ++e) {
      const float s = bf2f((unsigned short)v[e]);
      if (tj[e] != ti) {
        if (s + margin - mp > 0.0f) nsum += __expf(ALPHA * (s - BASE));
        if (last) { lsn += s; lcn += 1.0f; }
      } else if (s < 1.0f) {
        if (mx - s + margin > 0.0f) psum += __expf(-BETA * (s - BASE));
        if (last) { lsp += s; lcp += 1.0f; }
      }
    }
  }
  #pragma unroll
  for (int off = 1; off < 64; off <<= 1) {
    psum += __shfl_xor(psum, off);
    nsum += __shfl_xor(nsum, off);
  }
  if (last) {
    #pragma unroll
    for (int off = 1; off < 64; off <<= 1) {
      lsp += __shfl_xor(lsp, off); lcp += __shfl_xor(lcp, off);
      lsn += __shfl_xor(lsn, off); lcn += __shfl_xor(lcn, off);
    }
  }
  if (lane == 0) {
    const bool valid = (psum > 0.0f) && (nsum > 0.0f);
    rowloss[i] = valid ? (2.0f / BETA) * log1pf(psum) + (2.0f / ALPHA) * log1pf(nsum) : 0.0f;
    rowvalid[i] = valid ? 0.0f : 1.0f;
    if (last) { lacc[0] = lsp; lacc[1] = lcp; lacc[2] = lsn; lacc[3] = lcn; }
  }
}

__device__ __forceinline__ float block_sum(float v) {
  __shared__ float sh[4];
  #pragma unroll
  for (int off = 32; off > 0; off >>= 1) v += __shfl_down(v, off);
  if ((threadIdx.x & 63) == 0) sh[threadIdx.x >> 6] = v;
  __syncthreads();
  float r = sh[0] + sh[1] + sh[2] + sh[3];
  __syncthreads();
  return r;
}

__global__ __launch_bounds__(256) void finalize_k(
    const float* __restrict__ rowloss, const float* __restrict__ rowvalid,
    const float* __restrict__ lacc, float* __restrict__ out) {
  float lsum = 0.0f, inval = 0.0f;
  #pragma unroll
  for (int c = 0; c < 16; ++c) {
    const int i = c * 256 + threadIdx.x;
    lsum += rowloss[i];
    inval += rowvalid[i];
  }
  lsum = block_sum(lsum);
  inval = block_sum(inval);
  if (threadIdx.x == 0) {
    out[0] = lsum / (float)NROWS;
    out[1] = inval / (float)NROWS;
    out[2] = lacc[0] / fmaxf(lacc[1], 1.0f);
    out[3] = lacc[2] / fmaxf(lacc[3], 1.0f);
  }
}

extern "C" void kernel_launch(void* const* d_in, const int* in_sizes, int n_in,
                              void* d_out, int out_size, void* d_ws, size_t ws_size,
                              hipStream_t stream) {
  const float* X = (const float*)d_in[0];
  const int* tgt = (const int*)d_in[1];
  const float* marginp = (const float*)d_in[2];
  float* out = (float*)d_out;

  char* ws = (char*)d_ws;
  unsigned* minb = (unsigned*)ws;                       // @0     16 KB
  unsigned* maxb = (unsigned*)(ws + (16 << 10));        // @16K   16 KB
  float* rowloss = (float*)(ws + (32 << 10));           // @32K   16 KB
  float* rowvalid = (float*)(ws + (48 << 10));          // @48K   16 KB
  float* lacc = (float*)(ws + (64 << 10));              // @64K   small
  float* selfsim = (float*)(ws + (80 << 10));           // @80K   16 KB
  unsigned short* Xb = (unsigned short*)(ws + (128 << 10));                        // 4 MB
  unsigned short* simb = (unsigned short*)(ws + (128 << 10) + ((size_t)4 << 20));  // 32 MB

  convert_k<<<dim3(NROWS / 4), 256, 0, stream>>>(X, Xb, selfsim, minb, maxb, lacc);
  gemm_tri<<<dim3(NTRI), 256, 0, stream>>>(Xb, tgt, selfsim, minb, maxb, simb);
  row_pass<<<dim3(NROWS / 4), 256, 0, stream>>>(simb, tgt, minb, maxb, rowloss, rowvalid, lacc, marginp);
  finalize_k<<<dim3(1), 256, 0, stream>>>(rowloss, rowvalid, lacc, out);
}